// Round 1
// baseline (249.478 us; speedup 1.0000x reference)
//
#include <hip/hip_runtime.h>

// OFT rotation: out[n, r*64+c] = sum_k x[n, r*64+k] * R[r][k][c]
// R[r] = I + 2(Q + Q^2 + Q^3 + Q^4), Q skew-symmetric from strict-upper weights.

#define BS 64
#define NW 2016   // 64*63/2
#define LDP 68    // padded LDS row stride (float4-aligned, breaks pow2 bank stride)

// ---------------- Kernel 1: build R (64 blocks, one per rotation block) -------------

__device__ __forceinline__ void mm_tile_68(const float (*A)[LDP], const float (*Bm)[LDP],
                                           int r0, int c0, float p[4][4]) {
  // p += A[r0..r0+3][:] * Bm[:][c0..c0+3], K=64, stride LDP
  for (int k = 0; k < 64; k += 4) {
    float4 bv[4], av[4];
#pragma unroll
    for (int u = 0; u < 4; ++u) bv[u] = *(const float4*)&Bm[k + u][c0];
#pragma unroll
    for (int i = 0; i < 4; ++i) av[i] = *(const float4*)&A[r0 + i][k];
#pragma unroll
    for (int u = 0; u < 4; ++u) {
      const float4 b = bv[u];
#pragma unroll
      for (int i = 0; i < 4; ++i) {
        const float a = ((const float*)&av[i])[u];
        p[i][0] += a * b.x;
        p[i][1] += a * b.y;
        p[i][2] += a * b.z;
        p[i][3] += a * b.w;
      }
    }
  }
}

__global__ __launch_bounds__(256) void oft_build_R(const float* __restrict__ w,
                                                   float* __restrict__ Rout) {
  const int r = blockIdx.x;
  const int t = threadIdx.x;
  __shared__ float Q[BS][LDP];
  __shared__ float Pa[BS][LDP];
  __shared__ float Pb[BS][LDP];

  // zero Q (including pad)
  for (int f = t; f < BS * LDP; f += 256) (&Q[0][0])[f] = 0.f;
  __syncthreads();

  // scatter weights: strict upper triangle, row-major order (np.triu_indices(64,1))
  for (int i = t; i < NW; i += 256) {
    int row = 0, rem = i;
    while (rem >= 63 - row) { rem -= 63 - row; ++row; }
    const int col = row + 1 + rem;
    const float v = w[r * NW + i];
    Q[row][col] = v;
    Q[col][row] = -v;
  }
  __syncthreads();

  const int tr = t >> 4, tc = t & 15;
  const int r0 = tr * 4, c0 = tc * 4;

  float acc[4][4];
#pragma unroll
  for (int i = 0; i < 4; ++i)
#pragma unroll
    for (int j = 0; j < 4; ++j)
      acc[i][j] = ((r0 + i) == (c0 + j) ? 1.f : 0.f) + 2.f * Q[r0 + i][c0 + j];

  // P = Q*Q
  float p[4][4] = {};
  mm_tile_68(Q, Q, r0, c0, p);
#pragma unroll
  for (int i = 0; i < 4; ++i)
#pragma unroll
    for (int j = 0; j < 4; ++j) {
      Pa[r0 + i][c0 + j] = p[i][j];
      acc[i][j] += 2.f * p[i][j];
    }
  __syncthreads();

  // P2 = Pa*Q
  float p2[4][4] = {};
  mm_tile_68(Pa, Q, r0, c0, p2);
#pragma unroll
  for (int i = 0; i < 4; ++i)
#pragma unroll
    for (int j = 0; j < 4; ++j) {
      Pb[r0 + i][c0 + j] = p2[i][j];
      acc[i][j] += 2.f * p2[i][j];
    }
  __syncthreads();

  // P3 = Pb*Q (registers only)
  float p3[4][4] = {};
  mm_tile_68(Pb, Q, r0, c0, p3);
#pragma unroll
  for (int i = 0; i < 4; ++i)
#pragma unroll
    for (int j = 0; j < 4; ++j)
      acc[i][j] += 2.f * p3[i][j];

  // write R[r] (row-major 64x64), float4 per row
#pragma unroll
  for (int i = 0; i < 4; ++i) {
    float4 v = make_float4(acc[i][0], acc[i][1], acc[i][2], acc[i][3]);
    *(float4*)&Rout[(size_t)r * 4096 + (size_t)(r0 + i) * 64 + c0] = v;
  }
}

// ---------------- Kernel 2: apply block-diagonal rotation -------------

__global__ __launch_bounds__(256) void oft_apply(const float* __restrict__ x,
                                                 const float* __restrict__ R,
                                                 float* __restrict__ out) {
  const int r = blockIdx.x;     // rotation block 0..63
  const int tile = blockIdx.y;  // row tile 0..127
  const int t = threadIdx.x;

  __shared__ float Rs[BS * BS];     // 16 KB, flat (row-major, stride 64)
  __shared__ float Xs[BS][LDP];     // 64 rows x 64 (padded to 68)

  const int n0 = tile * 64;

  // stage R[r]: 1024 float4, 256 threads x 4
  const float4* Rg = (const float4*)(R + (size_t)r * 4096);
  float4* Rs4 = (float4*)Rs;
#pragma unroll
  for (int i = 0; i < 4; ++i) Rs4[t + 256 * i] = Rg[t + 256 * i];

  // stage x tile: 64 rows x 16 float4
#pragma unroll
  for (int i = 0; i < 4; ++i) {
    const int f = t + 256 * i;       // 0..1023
    const int row = f >> 4;
    const int c4 = (f & 15) << 2;
    *(float4*)&Xs[row][c4] =
        *(const float4*)&x[(size_t)(n0 + row) * 4096 + r * 64 + c4];
  }
  __syncthreads();

  const int tr = t >> 4, tc = t & 15;
  const int c0 = tc * 4, rr0 = tr * 4;

  float acc[4][4] = {};
#pragma unroll 4
  for (int k = 0; k < 64; k += 4) {
    float4 bv[4], av[4];
#pragma unroll
    for (int u = 0; u < 4; ++u) bv[u] = *(const float4*)&Rs[(k + u) * 64 + c0];
#pragma unroll
    for (int i = 0; i < 4; ++i) av[i] = *(const float4*)&Xs[rr0 + i][k];
#pragma unroll
    for (int u = 0; u < 4; ++u) {
      const float4 b = bv[u];
#pragma unroll
      for (int i = 0; i < 4; ++i) {
        const float a = ((const float*)&av[i])[u];
        acc[i][0] += a * b.x;
        acc[i][1] += a * b.y;
        acc[i][2] += a * b.z;
        acc[i][3] += a * b.w;
      }
    }
  }

#pragma unroll
  for (int i = 0; i < 4; ++i) {
    float4 v = make_float4(acc[i][0], acc[i][1], acc[i][2], acc[i][3]);
    *(float4*)&out[(size_t)(n0 + rr0 + i) * 4096 + r * 64 + c0] = v;
  }
}

extern "C" void kernel_launch(void* const* d_in, const int* in_sizes, int n_in,
                              void* d_out, int out_size, void* d_ws, size_t ws_size,
                              hipStream_t stream) {
  const float* x = (const float*)d_in[0];   // (8192, 4096) fp32
  const float* w = (const float*)d_in[1];   // (64, 2016) fp32
  float* out = (float*)d_out;               // (8192, 4096) fp32
  float* Rws = (float*)d_ws;                // 64*64*64 fp32 = 1 MB scratch

  oft_build_R<<<64, 256, 0, stream>>>(w, Rws);
  oft_apply<<<dim3(64, 128), 256, 0, stream>>>(x, Rws, out);
}